// Round 12
// baseline (1240.712 us; speedup 1.0000x reference)
//
#include <hip/hip_runtime.h>

#define U_N 100000
#define I_N 50000
#define D_N 64
#define B_N 4
#define E_N 2000000

#define EDGES   (B_N * E_N)            // 8,000,000 edge-entries per side
#define NSC_U   (U_N / 8)              // 12,500 chunks (8 rows x 4 behaviors)
#define NSC_I   (I_N / 8)              // 6,250 item chunks
#define NBLK    256                    // pass-A partition blocks (32 per XCD)
#define EPB     (EDGES / NBLK)         // 31,250 entries per block (exact)
#define XSTR    36                     // xs leading stride (dwords)

// Bucketing: user side 500 buckets x 25 chunks; item side 625 x 10.
// Bin key within bucket: (chunk_in_bucket<<5) | ((k&7)<<2) | behavior.
// payA_K/payB = bf16val-sans-sign(15b)<<17 | src(17b). payA_L = bin (u16).

// ---------------------------------------------------------------------------
// Pass 0: convert both embedding tables to bf16 (RNE).
// ---------------------------------------------------------------------------
__global__ __launch_bounds__(256) void cvt_kernel(const float* __restrict__ ue,
                                                  const float* __restrict__ ie,
                                                  unsigned short* __restrict__ u16,
                                                  unsigned short* __restrict__ i16) {
    int i = blockIdx.x * 256 + threadIdx.x;
    int nu = U_N * D_N;
    int ni = I_N * D_N;
    if (i < nu) {
        unsigned u = __float_as_uint(ue[i]);
        u += 0x7FFFu + ((u >> 16) & 1u);
        u16[i] = (unsigned short)(u >> 16);
    } else if (i < nu + ni) {
        int j = i - nu;
        unsigned u = __float_as_uint(ie[j]);
        u += 0x7FFFu + ((u >> 16) & 1u);
        i16[j] = (unsigned short)(u >> 16);
    }
}

// ---------------------------------------------------------------------------
// Pass A1: per-(block, bucket) histogram. Tiny LDS (NBKT ints).
// ---------------------------------------------------------------------------
template <int NBKT, int BKT_CH>
__global__ __launch_bounds__(1024) void histA_kernel(const int* __restrict__ keys,
                                                     int* __restrict__ cntA) {
    __shared__ int h[NBKT];
    for (int i = threadIdx.x; i < NBKT; i += 1024) h[i] = 0;
    __syncthreads();
    int lb = ((blockIdx.x & 7) << 5) | (blockIdx.x >> 3);   // XCD-major
    int base = lb * EPB;
    for (int i = threadIdx.x; i < EPB; i += 1024)
        atomicAdd(&h[(keys[base + i] >> 3) / BKT_CH], 1);
    __syncthreads();
    int* row = cntA + (size_t)lb * NBKT;
    for (int i = threadIdx.x; i < NBKT; i += 1024) row[i] = h[i];
}

// ---------------------------------------------------------------------------
// Pass A2: bucket totals -> exclusive scan -> per-block cursors in place.
// Single block.
// ---------------------------------------------------------------------------
template <int NBKT>
__global__ __launch_bounds__(1024) void scanA_kernel(int* __restrict__ cntA,
                                                     int* __restrict__ offBkt) {
    int t = threadIdx.x;
    int s = 0;
    if (t < NBKT)
        for (int lb = 0; lb < NBLK; ++lb) s += cntA[(size_t)lb * NBKT + t];
    __shared__ int sm[1024];
    sm[t] = (t < NBKT) ? s : 0;
    __syncthreads();
    for (int o = 1; o < 1024; o <<= 1) {
        int a = (t >= o) ? sm[t - o] : 0;
        __syncthreads(); sm[t] += a; __syncthreads();
    }
    int pre = sm[t] - ((t < NBKT) ? s : 0);
    if (t < NBKT) {
        offBkt[t] = pre;
        int run = pre;
        for (int lb = 0; lb < NBLK; ++lb) {
            int c = cntA[(size_t)lb * NBKT + t];
            cntA[(size_t)lb * NBKT + t] = run;
            run += c;
        }
    }
    if (t == 0) offBkt[NBKT] = EDGES;
}

// ---------------------------------------------------------------------------
// Pass A3: coarse placement into buckets. LDS cursors (NBKT), zero global
// atomics; frontier ~NBKT lines/block -> L2-resident full-line writebacks.
// ---------------------------------------------------------------------------
template <int NBKT, int BKT_CH>
__global__ __launch_bounds__(1024) void cplaceA_kernel(
        const int* __restrict__ keys,
        const int* __restrict__ srcs,
        const float* __restrict__ vals,
        const int* __restrict__ curA,
        unsigned* __restrict__ payA_K,
        unsigned short* __restrict__ payA_L) {
    __shared__ int cur[NBKT];
    int lb = ((blockIdx.x & 7) << 5) | (blockIdx.x >> 3);
    const int* crow = curA + (size_t)lb * NBKT;
    for (int i = threadIdx.x; i < NBKT; i += 1024) cur[i] = crow[i];
    __syncthreads();
    int base = lb * EPB;
    int b = lb >> 6;                     // behavior: 64 blocks per behavior
    for (int i = threadIdx.x; i < EPB; i += 1024) {
        int gi = base + i;
        int k = keys[gi];
        int chunk = k >> 3;
        int bkt = chunk / BKT_CH;        // constant divisor -> magic mul
        int cib = chunk - bkt * BKT_CH;
        unsigned u = __float_as_uint(vals[gi]);   // vals > 0 -> sign bit 0
        u += 0x7FFFu + ((u >> 16) & 1u);
        unsigned bf15 = (u >> 16) & 0x7FFFu;
        int pos = atomicAdd(&cur[bkt], 1);
        payA_K[pos] = (bf15 << 17) | (unsigned)srcs[gi];
        payA_L[pos] = (unsigned short)((cib << 5) | ((k & 7) << 2) | b);
    }
}

// ---------------------------------------------------------------------------
// Pass B: one block per bucket. LDS counting-sort by bin (BKT_CH*32 bins);
// writes bin-sorted payB + absolute bin starts (binoff). Frontier = NBIN
// cursors (~51 KB of lines) -> fully L2-resident.
// ---------------------------------------------------------------------------
template <int BKT_CH>
__global__ __launch_bounds__(1024) void cplaceB_kernel(
        const unsigned* __restrict__ payA_K,
        const unsigned short* __restrict__ payA_L,
        const int* __restrict__ offBkt,
        int nbkt,
        unsigned* __restrict__ payB,
        int* __restrict__ binoff) {
    const int NBIN = BKT_CH * 32;
    int bk = blockIdx.x;
    int base = offBkt[bk], n = offBkt[bk + 1] - base;
    int t = threadIdx.x;
    __shared__ int h[NBIN];
    __shared__ int cur[NBIN];
    __shared__ int sm[1024];
    for (int i = t; i < NBIN; i += 1024) h[i] = 0;
    __syncthreads();
    for (int i = t; i < n; i += 1024)
        atomicAdd(&h[payA_L[base + i]], 1);
    __syncthreads();
    int v = (t < NBIN) ? h[t] : 0;
    sm[t] = v;
    __syncthreads();
    for (int o = 1; o < 1024; o <<= 1) {
        int a = (t >= o) ? sm[t - o] : 0;
        __syncthreads(); sm[t] += a; __syncthreads();
    }
    if (t < NBIN) {
        int st = base + sm[t] - v;
        cur[t] = st;
        binoff[(size_t)bk * NBIN + t] = st;
    }
    if (bk == nbkt - 1 && t == 0)
        binoff[(size_t)nbkt * NBIN] = EDGES;      // sentinel = NSC*32 slot
    __syncthreads();
    for (int i = t; i < n; i += 1024) {
        int pos = atomicAdd(&cur[payA_L[base + i]], 1);
        payB[pos] = payA_K[base + i];
    }
}

// ---------------------------------------------------------------------------
// Fused: pure accumulate + transform. No sort, no block barriers. Wave w
// owns bins w*4..w*4+3 of chunk g (bounds from binoff); quad-row register
// accumulate; d-major xs (intra-wave); 64x64 transform + sigmoid + mean.
// LDS 9.2 KB.
// ---------------------------------------------------------------------------
__global__ __launch_bounds__(512) void fused_kernel(
        const unsigned short* __restrict__ emb16,
        const float* __restrict__ W,
        const int* __restrict__ binoff,
        const unsigned* __restrict__ payB,
        float* __restrict__ embs,        // [B][nrows][64] <- sigmoid(x@W)
        float* __restrict__ mean_out,    // [nrows][64]    <- sigmoid(mean@W)
        int nrows) {
    int g = blockIdx.x;
    int t = threadIdx.x, w = t >> 6, lane = t & 63;
    __shared__ float xs[64 * XSTR];      // 9.2 KB d-major accumulators

    int qt = lane >> 4, ql = lane & 15;
    float4 a0, a1, a2, a3;
#define ACC_BIN(AQ, Q)                                                        \
    {                                                                         \
        int s0 = binoff[g * 32 + w * 4 + (Q)];                                \
        int s1 = binoff[g * 32 + w * 4 + (Q) + 1];                            \
        AQ = make_float4(0.f, 0.f, 0.f, 0.f);                                 \
        for (int j = s0; j < s1; j += 4) {                                    \
            int idx = j + qt;                                                 \
            int jj = idx < s1 ? idx : s1 - 1;                                 \
            unsigned p = payB[jj];                                            \
            float v = (idx < s1)                                              \
                ? __uint_as_float((p & 0xFFFE0000u) >> 1) : 0.f;              \
            uint2 x = *((const uint2*)(emb16 +                                \
                          (size_t)(p & 0x1FFFFu) * 64) + ql);                 \
            AQ.x = fmaf(v, __uint_as_float(x.x << 16), AQ.x);                 \
            AQ.y = fmaf(v, __uint_as_float(x.x & 0xFFFF0000u), AQ.y);         \
            AQ.z = fmaf(v, __uint_as_float(x.y << 16), AQ.z);                 \
            AQ.w = fmaf(v, __uint_as_float(x.y & 0xFFFF0000u), AQ.w);         \
        }                                                                     \
        AQ.x += __shfl_xor(AQ.x, 16); AQ.x += __shfl_xor(AQ.x, 32);           \
        AQ.y += __shfl_xor(AQ.y, 16); AQ.y += __shfl_xor(AQ.y, 32);           \
        AQ.z += __shfl_xor(AQ.z, 16); AQ.z += __shfl_xor(AQ.z, 32);           \
        AQ.w += __shfl_xor(AQ.w, 16); AQ.w += __shfl_xor(AQ.w, 32);           \
    }
    ACC_BIN(a0, 0)
    ACC_BIN(a1, 1)
    ACC_BIN(a2, 2)
    ACC_BIN(a3, 3)
#undef ACC_BIN
    if (qt == 0) {                       // intra-wave dep with transform reads
        *(float4*)&xs[(4 * ql + 0) * XSTR + w * 4] =
            make_float4(a0.x, a1.x, a2.x, a3.x);
        *(float4*)&xs[(4 * ql + 1) * XSTR + w * 4] =
            make_float4(a0.y, a1.y, a2.y, a3.y);
        *(float4*)&xs[(4 * ql + 2) * XSTR + w * 4] =
            make_float4(a0.z, a1.z, a2.z, a3.z);
        *(float4*)&xs[(4 * ql + 3) * XSTR + w * 4] =
            make_float4(a0.w, a1.w, a2.w, a3.w);
    }

    // Transform: y[q][lane] = sum_d xs[d][w*4+q] * W[d][lane].
    float y[4] = {0.f, 0.f, 0.f, 0.f};
#pragma unroll 4
    for (int d = 0; d < 64; ++d) {
        float4 xq = *(const float4*)&xs[d * XSTR + w * 4];
        float wv = W[d * 64 + lane];
        y[0] = fmaf(xq.x, wv, y[0]);
        y[1] = fmaf(xq.y, wv, y[1]);
        y[2] = fmaf(xq.z, wv, y[2]);
        y[3] = fmaf(xq.w, wv, y[3]);
    }
    int row = g * 8 + w;
#pragma unroll
    for (int q = 0; q < 4; ++q)
        embs[((long long)q * nrows + row) * 64 + lane] =
            1.f / (1.f + __expf(-y[q]));
    float m = 0.25f * (y[0] + y[1] + y[2] + y[3]);
    mean_out[(long long)row * 64 + lane] = 1.f / (1.f + __expf(-m));
}

// ---------------------------------------------------------------------------
// Deep fallback: atomic scatter + separate transform (only if ws too small).
// ---------------------------------------------------------------------------
__global__ void scatter_atomic_kernel(const float* __restrict__ user_emb,
                                      const float* __restrict__ item_emb,
                                      const int* __restrict__ rows,
                                      const int* __restrict__ cols,
                                      const float* __restrict__ vals,
                                      float* __restrict__ stack_u,
                                      float* __restrict__ stack_i) {
    long long tid = (long long)blockIdx.x * blockDim.x + threadIdx.x;
    long long e  = tid >> 4;
    int lane = (int)(tid & 15);
    if (e >= (long long)EDGES) return;
    int b = (int)(e / E_N);
    int r = rows[e];
    int c = cols[e];
    float v = vals[e];
    const float4* irow = (const float4*)(item_emb + (long long)c * D_N);
    const float4* urow = (const float4*)(user_emb + (long long)r * D_N);
    float4 iv = irow[lane];
    float4 uv = urow[lane];
    float* du = stack_u + ((long long)b * U_N + r) * D_N + lane * 4;
    float* di = stack_i + ((long long)b * I_N + c) * D_N + lane * 4;
    atomicAdd(du + 0, v * iv.x);
    atomicAdd(du + 1, v * iv.y);
    atomicAdd(du + 2, v * iv.z);
    atomicAdd(du + 3, v * iv.w);
    atomicAdd(di + 0, v * uv.x);
    atomicAdd(di + 1, v * uv.y);
    atomicAdd(di + 2, v * uv.z);
    atomicAdd(di + 3, v * uv.w);
}

template <int NROWS>
__global__ __launch_bounds__(64) void transform_kernel(
        float* __restrict__ stack,
        const float* __restrict__ W,
        float* __restrict__ mean_out) {
    const int row = blockIdx.x;
    const int j   = threadIdx.x;
    __shared__ float xs[B_N][D_N];
#pragma unroll
    for (int b = 0; b < B_N; ++b)
        xs[b][j] = stack[((long long)b * NROWS + row) * D_N + j];
    __syncthreads();
    float acc[B_N] = {0.f, 0.f, 0.f, 0.f};
#pragma unroll 8
    for (int d = 0; d < D_N; ++d) {
        float w = W[d * D_N + j];
#pragma unroll
        for (int b = 0; b < B_N; ++b)
            acc[b] += xs[b][d] * w;
    }
    float m = 0.25f * (acc[0] + acc[1] + acc[2] + acc[3]);
#pragma unroll
    for (int b = 0; b < B_N; ++b)
        stack[((long long)b * NROWS + row) * D_N + j] =
            1.0f / (1.0f + __expf(-acc[b]));
    mean_out[(long long)row * D_N + j] = 1.0f / (1.0f + __expf(-m));
}

// ---------------------------------------------------------------------------
extern "C" void kernel_launch(void* const* d_in, const int* in_sizes, int n_in,
                              void* d_out, int out_size, void* d_ws, size_t ws_size,
                              hipStream_t stream) {
    const float* user_emb = (const float*)d_in[0];
    const float* item_emb = (const float*)d_in[1];
    const int*   rows     = (const int*)  d_in[2];
    const int*   cols     = (const int*)  d_in[3];
    const float* vals     = (const float*)d_in[4];
    const float* u_w      = (const float*)d_in[5];
    const float* i_w      = (const float*)d_in[6];

    float* out = (float*)d_out;
    float* user_mean = out;
    float* item_mean = out + (long long)U_N * D_N;
    float* stack_u   = item_mean + (long long)I_N * D_N;     // user_embs out
    float* stack_i   = stack_u + (long long)B_N * U_N * D_N; // item_embs out

    // Workspace (~101 MB): payA_K | payB | payA_L | user16 | item16 |
    //                      cntA [256][625] | offBkt [626] | binoff [400001]
    unsigned* payA_K = (unsigned*)d_ws;                            // 32 MB
    unsigned* payB   = payA_K + EDGES;                             // 32 MB
    unsigned short* payA_L = (unsigned short*)(payB + EDGES);      // 16 MB
    unsigned short* user16 = payA_L + (size_t)EDGES;               // 12.8 MB
    unsigned short* item16 = user16 + (size_t)U_N * D_N;           // 6.4 MB
    int* cntA   = (int*)(item16 + (size_t)I_N * D_N);              // 640 KB
    int* offBkt = cntA + (size_t)NBLK * 625;                       // 2.5 KB
    int* binoff = offBkt + 626;                                    // 1.6 MB
    size_t needed = ((char*)(binoff + (size_t)NSC_U * 32 + 1)) - (char*)d_ws;

    if (ws_size >= needed) {
        int ncvt = (U_N + I_N) * D_N;
        cvt_kernel<<<(ncvt + 255) / 256, 256, 0, stream>>>(user_emb, item_emb,
                                                           user16, item16);
        // ---- user side: keys=rows, gathers item table. 500 buckets x 25 ----
        histA_kernel<500, 25><<<NBLK, 1024, 0, stream>>>(rows, cntA);
        scanA_kernel<500><<<1, 1024, 0, stream>>>(cntA, offBkt);
        cplaceA_kernel<500, 25><<<NBLK, 1024, 0, stream>>>(rows, cols, vals,
                                                           cntA, payA_K, payA_L);
        cplaceB_kernel<25><<<500, 1024, 0, stream>>>(payA_K, payA_L, offBkt,
                                                     500, payB, binoff);
        fused_kernel<<<NSC_U, 512, 0, stream>>>(item16, u_w, binoff, payB,
                                                stack_u, user_mean, U_N);
        // ---- item side: keys=cols, gathers user table. 625 buckets x 10 ----
        histA_kernel<625, 10><<<NBLK, 1024, 0, stream>>>(cols, cntA);
        scanA_kernel<625><<<1, 1024, 0, stream>>>(cntA, offBkt);
        cplaceA_kernel<625, 10><<<NBLK, 1024, 0, stream>>>(cols, rows, vals,
                                                           cntA, payA_K, payA_L);
        cplaceB_kernel<10><<<625, 1024, 0, stream>>>(payA_K, payA_L, offBkt,
                                                     625, payB, binoff);
        fused_kernel<<<NSC_I, 512, 0, stream>>>(user16, i_w, binoff, payB,
                                                stack_i, item_mean, I_N);
    } else {
        size_t stack_bytes = sizeof(float) * (size_t)B_N * (U_N + I_N) * D_N;
        hipMemsetAsync(stack_u, 0, stack_bytes, stream);
        long long nthreads = (long long)EDGES * 16;
        int nblocks = (int)((nthreads + 255) / 256);
        scatter_atomic_kernel<<<nblocks, 256, 0, stream>>>(
            user_emb, item_emb, rows, cols, vals, stack_u, stack_i);
        transform_kernel<U_N><<<U_N, 64, 0, stream>>>(stack_u, u_w, user_mean);
        transform_kernel<I_N><<<I_N, 64, 0, stream>>>(stack_i, i_w, item_mean);
    }
}